// Round 11
// baseline (367.907 us; speedup 1.0000x reference)
//
#include <hip/hip_runtime.h>
#include <hip/hip_fp16.h>
#include <cstdint>

// Problem constants (setup_inputs: B=8, H=W=512, num_erosions=2)
static constexpr int B = 8;
static constexpr int H = 512;
static constexpr int W = 512;
static constexpr int HW = H * W;
static constexpr int NPIX = B * HW;
static constexpr int NB1 = 1024;  // blocks for cross_max partials
static constexpr int NBD = 1024;  // blocks per dil_diff level

// 10*log2(e): sigmoid(10*z) = 1/(1+2^(-CC*z))
static constexpr float CC = 14.4269504088896f;

// ---------------- helpers ----------------------------------------------------
// Raw v_exp_f32/v_rcp_f32 via builtins (R4: ocml exp = ~12 inst). No
// multi-block atomics (R5: same-line atomic chain serializes device-wide).
// Straight-line sigmoids (R3: wave-vote branches killed ILP). Mega dispatches
// co-schedule memory-bound aux blocks with VALU-bound cp blocks (R11; m114).
__device__ __forceinline__ float rcpf(float x) { return __builtin_amdgcn_rcpf(x); }
__device__ __forceinline__ float exp2f_n(float x) { return __builtin_amdgcn_exp2f(x); }
__device__ __forceinline__ float endsig(float nc) {
    return rcpf(1.0f + exp2f_n(fmaf(nc, CC, -CC)));
}
__device__ __forceinline__ float endsig_c(float nc, float cm) {
    return rcpf(1.0f + exp2f_n(fmaf(nc, -CC, cm)));
}
__device__ __forceinline__ float sig_cp(float x) {  // sigmoid(10(x-0.5))
    return rcpf(1.0f + exp2f_n(fmaf(x, -CC, 0.5f * CC)));
}
__device__ __forceinline__ float sig_er(float r) {  // sigmoid(10(r-0.7))
    return rcpf(1.0f + exp2f_n(fmaf(r, -CC, 0.7f * CC)));
}
__device__ __forceinline__ float wave_max(float m) {
#pragma unroll
    for (int o = 32; o > 0; o >>= 1) m = fmaxf(m, __shfl_down(m, o, 64));
    return m;
}
__device__ __forceinline__ float wave_sum(float s) {
#pragma unroll
    for (int o = 32; o > 0; o >>= 1) s += __shfl_down(s, o, 64);
    return s;
}

// Redundant per-block PM reduce (16KB, L2-resident). Same tree as R10's
// erode reduce -> bitwise-identical maxes.
__device__ __forceinline__ void pm_reduce(const float4* __restrict__ PM,
                                          float& a, float& bm, float& c4,
                                          float& d4) {
    a = 0; bm = 0; c4 = 0; d4 = 0;
    int t = threadIdx.x;
#pragma unroll
    for (int k = 0; k < NB1 / 256; k++) {
        float4 p = PM[t + k * 256];
        a = fmaxf(a, p.x); bm = fmaxf(bm, p.y);
        c4 = fmaxf(c4, p.z); d4 = fmaxf(d4, p.w);
    }
    a = wave_max(a); bm = wave_max(bm); c4 = wave_max(c4); d4 = wave_max(d4);
    __shared__ float red[4][4];
    if ((t & 63) == 0) {
        int w = t >> 6;
        red[w][0] = a; red[w][1] = bm; red[w][2] = c4; red[w][3] = d4;
    }
    __syncthreads();
    a  = fmaxf(fmaxf(red[0][0], red[1][0]), fmaxf(red[2][0], red[3][0]));
    bm = fmaxf(fmaxf(red[0][1], red[1][1]), fmaxf(red[2][1], red[3][1]));
    c4 = fmaxf(fmaxf(red[0][2], red[1][2]), fmaxf(red[2][2], red[3][2]));
    d4 = fmaxf(fmaxf(red[0][3], red[1][3]), fmaxf(red[2][3], red[3][3]));
}

// ---------------- row-sweep mask conv sums (unchanged) -----------------------
struct NC {
    float n3[8], n4[8], n5[8], n6[7];
    float v;  // center value w[3][3]
};

template <int STRIDE>
__device__ __forceinline__ NC sweep(const float* rp) {
    NC o;
    float r2s, r3s, r4s;
    float cen0, cen1, cen2, cen3, cen4, cen5, cen6, cen7, cen8;
    {   // win row 0 = K6 row 0
        float c0 = rp[0], c1 = rp[1], c2 = rp[2], c3 = rp[3], c4 = rp[4], c5 = rp[5];
        float c45 = c4 + c5, c01 = c0 + c1;
        float S6 = (c01 + (c2 + c3)) + c45;
        o.n6[0] = c45; o.n6[1] = c01; o.n6[2] = S6; o.n6[3] = S6;
        o.n6[4] = S6;  o.n6[5] = S6;  o.n6[6] = S6;
    }
    rp += STRIDE;
    {   // win row 1 = K6 r1, K5 r0, K4 r0
        float c0 = rp[0], c1 = rp[1], c2 = rp[2], c3 = rp[3], c4 = rp[4], c5 = rp[5];
        float c45 = c4 + c5, c12 = c1 + c2, c34 = c3 + c4;
        float S4 = c12 + c34, S5 = S4 + c5;
        float c15 = c1 + c5, c05 = c0 + c5, c14 = c1 + c4;
        o.n6[0] += c5;  o.n6[1] += c0;  o.n6[2] += c05; o.n6[3] += c05;
        o.n6[4] += c0;  o.n6[5] += c5;  o.n6[6] += c05;
        o.n5[0] = c45; o.n5[1] = c12; o.n5[2] = S5; o.n5[3] = S5;
        o.n5[4] = S5;  o.n5[5] = S5;  o.n5[6] = S5; o.n5[7] = c15;
        o.n4[0] = c34; o.n4[1] = c12; o.n4[2] = S4; o.n4[3] = S4;
        o.n4[4] = c14; o.n4[5] = S4;  o.n4[6] = S4; o.n4[7] = S4;
    }
    rp += STRIDE;
    {   // win row 2 = K6 r2, K5 r1, K4 r1, K3 r0
        float c0 = rp[0], c1 = rp[1], c2 = rp[2], c3 = rp[3], c4 = rp[4], c5 = rp[5];
        float c05 = c0 + c5, c15 = c1 + c5, c14 = c1 + c4;
        r2s = (c2 + c3) + c4;
        cen0 = c2; cen1 = c3; cen2 = c4;
        o.n6[0] += c5;  o.n6[1] += c0;  o.n6[2] += c0;  o.n6[3] += c5;
        o.n6[4] += c0;  o.n6[5] += c5;  o.n6[6] += c05;
        o.n5[0] += c5;  o.n5[1] += c1;  o.n5[2] += c15; o.n5[3] += c15;
        o.n5[4] += c1;  o.n5[5] += c5;  o.n5[6] += c15; o.n5[7] += c15;
        o.n4[0] += c4;  o.n4[1] += c1;  o.n4[2] += c14; o.n4[3] += c14;
        o.n4[4] += c14; o.n4[5] += c4;  o.n4[6] += c14; o.n4[7] += c1;
    }
    rp += STRIDE;
    {   // win row 3 = K6 r3, K5 r2, K4 r2, K3 r1 (center row)
        float c0 = rp[0], c1 = rp[1], c2 = rp[2], c3 = rp[3], c4 = rp[4], c5 = rp[5];
        float c05 = c0 + c5, c15 = c1 + c5, c14 = c1 + c4;
        r3s = (c2 + c3) + c4;
        cen3 = c2; cen4 = c3; cen5 = c4;
        o.v = c3;
        o.n6[0] += c5;  o.n6[1] += c0;  o.n6[2] += c0;  o.n6[3] += c5;
        o.n6[4] += c0;  o.n6[5] += c5;  o.n6[6] += c05;
        o.n5[0] += c5;  o.n5[1] += c1;  o.n5[2] += c1;  o.n5[3] += c5;
        o.n5[4] += c1;  o.n5[5] += c5;  o.n5[6] += c15; o.n5[7] += c15;
        o.n4[0] += c14; o.n4[1] += c14; o.n4[2] += c4;  o.n4[3] += c1;
        o.n4[4] += c14; o.n4[5] += c4;  o.n4[6] += c14; o.n4[7] += c1;
    }
    rp += STRIDE;
    {   // win row 4 = K6 r4, K5 r3, K4 r3, K3 r2
        float c0 = rp[0], c1 = rp[1], c2 = rp[2], c3 = rp[3], c4 = rp[4], c5 = rp[5];
        float c05 = c0 + c5, c15 = c1 + c5, c12 = c1 + c2, c34 = c3 + c4;
        float S4 = c12 + c34, c14 = c1 + c4;
        r4s = (c2 + c3) + c4;
        cen6 = c2; cen7 = c3; cen8 = c4;
        o.n6[0] += c05; o.n6[1] += c05; o.n6[2] += c0;  o.n6[3] += c5;
        o.n6[4] += c0;  o.n6[5] += c5;  o.n6[6] += c05;
        o.n5[0] += c15; o.n5[1] += c15; o.n5[2] += c1;  o.n5[3] += c5;
        o.n5[4] += c1;  o.n5[5] += c5;  o.n5[6] += c15; o.n5[7] += c15;
        o.n4[0] += S4;  o.n4[1] += S4;  o.n4[2] += c34; o.n4[3] += c12;
        o.n4[4] += S4;  o.n4[5] += S4;  o.n4[6] += c14; o.n4[7] += S4;
    }
    rp += STRIDE;
    {   // win row 5 = K6 r5, K5 r4
        float c0 = rp[0], c1 = rp[1], c2 = rp[2], c3 = rp[3], c4 = rp[4], c5 = rp[5];
        float c45 = c4 + c5, c12 = c1 + c2;
        float t = c3 + c45, S5 = c12 + t, S6 = S5 + c0;
        float c01 = c0 + c1, c05 = c0 + c5, c15 = c1 + c5;
        o.n6[0] += S6;  o.n6[1] += S6;  o.n6[2] += c01; o.n6[3] += c45;
        o.n6[4] += S6;  o.n6[5] += S6;  o.n6[6] += c05;
        o.n5[0] += S5;  o.n5[1] += S5;  o.n5[2] += c12; o.n5[3] += c45;
        o.n5[4] += S5;  o.n5[5] += S5;  o.n5[6] += c15; o.n5[7] += S5;
    }
    // K3: all 8 masks = S33 - center - one distinct cell
    float S33 = (r2s + r3s) + r4s;
    float T = S33 - cen4;
    o.n3[0] = T - cen3; o.n3[1] = T - cen7; o.n3[2] = T - cen5; o.n3[3] = T - cen1;
    o.n3[4] = T - cen0; o.n3[5] = T - cen6; o.n3[6] = T - cen8; o.n3[7] = T - cen2;
    return o;
}

// complement-const index per mask into cm[6] = CC*({7,9,10,11,13,16}*M - 1)
__constant__ __device__ const int CI4[8] = {1, 1, 1, 1, 2, 2, 2, 2};
__constant__ __device__ const int CI5[8] = {3, 3, 3, 3, 4, 4, 4, 4};
__constant__ __device__ const int CI6[7] = {4, 4, 4, 4, 5, 5, 5};

template <bool PAIR>
__device__ __forceinline__ void ssum_from_nc(const NC& a, const float* cm,
                                             float& sD, float& sC) {
    float sd = 0.0f, sc = 0.0f;
#pragma unroll
    for (int k = 0; k < 8; k++) {
        sd += endsig(a.n3[k]);
        if constexpr (PAIR) sc += endsig_c(a.n3[k], cm[0]);
    }
#pragma unroll
    for (int k = 0; k < 8; k++) {
        sd += endsig(a.n4[k]);
        if constexpr (PAIR) sc += endsig_c(a.n4[k], cm[CI4[k]]);
    }
#pragma unroll
    for (int k = 0; k < 8; k++) {
        sd += endsig(a.n5[k]);
        if constexpr (PAIR) sc += endsig_c(a.n5[k], cm[CI5[k]]);
    }
#pragma unroll
    for (int k = 0; k < 7; k++) {
        sd += endsig(a.n6[k]);
        if constexpr (PAIR) sc += endsig_c(a.n6[k], cm[CI6[k]]);
    }
    sD = sd;
    sC = sc;
}

// ---------------- cross-conv 4px/thread helper -------------------------------
__device__ __forceinline__ void cross4(const float* __restrict__ xp, int idx,
                                       int y, int c, float4& ctr, float t[4]) {
    const float4* v = (const float4*)(xp + idx);
    ctr = v[0];
    float4 up = (y > 0) ? *(const float4*)(xp + idx - W)
                        : make_float4(0, 0, 0, 0);
    float4 dn = (y < H - 1) ? *(const float4*)(xp + idx + W)
                            : make_float4(0, 0, 0, 0);
    float lf = (c > 0) ? xp[idx - 1] : 0.0f;
    float rt = (c < W - 4) ? xp[idx + 4] : 0.0f;
    t[0] = (up.x + dn.x) + (lf + ctr.y);
    t[1] = (up.y + dn.y) + (ctr.x + ctr.z);
    t[2] = (up.z + dn.z) + (ctr.y + ctr.w);
    t[3] = (up.w + dn.w) + (ctr.z + rt);
}

// ---------------- dil rows helper (f16 input) --------------------------------
__device__ __forceinline__ void dil_rows10(const __half* __restrict__ p,
                                           int base, int y0, int x,
                                           float rs[10]) {
#pragma unroll
    for (int j = 0; j < 10; j++) {
        int yy = y0 - 1 + j;
        float l = 0, m = 0, r = 0;
        if (yy >= 0 && yy < H) {  // wave-uniform
            int rb = base + yy * W;
            m = __half2float(p[rb + x]);
            int xl = x > 0 ? x - 1 : 0;
            int xr = x < W - 1 ? x + 1 : W - 1;
            float lv = __half2float(p[rb + xl]);
            float rv = __half2float(p[rb + xr]);
            l = x > 0 ? lv : 0.0f;
            r = x < W - 1 ? rv : 0.0f;
        }
        rs[j] = (l + m) + r;
    }
}

__device__ __forceinline__ void dil_body(const __half* __restrict__ cpb, int r,
                                         float* __restrict__ partial_slot) {
    const int T = r * 256 + threadIdx.x;
    const int x = T & (W - 1);
    const int g = T >> 9;
    const int y0 = (g & 63) << 3;  // 64 rowgroups of 8 rows
    const int b = g >> 6;
    const int base = b * HW;

    float rs0[10], rs1[10], rs2[10], rs3[10];
    dil_rows10(cpb + 0 * NPIX, base, y0, x, rs0);
    dil_rows10(cpb + 1 * NPIX, base, y0, x, rs1);
    dil_rows10(cpb + 2 * NPIX, base, y0, x, rs2);
    dil_rows10(cpb + 3 * NPIX, base, y0, x, rs3);

    float s = 0.0f;
#pragma unroll
    for (int i = 0; i < 8; i++) {
        float s0 = (rs0[i] + rs0[i + 1]) + rs0[i + 2];
        float s1 = (rs1[i] + rs1[i + 1]) + rs1[i + 2];
        float s2 = (rs2[i] + rs2[i + 1]) + rs2[i + 2];
        float s3 = (rs3[i] + rs3[i + 1]) + rs3[i + 2];
        float d1 = fminf(s0, 1.0f) - fminf(s1, 1.0f);
        float d2 = fminf(s2, 1.0f) - fminf(s3, 1.0f);
        s += fmaf(d1, d1, d2 * d2);
    }
    s = wave_sum(s);
    __shared__ float red[4];
    int tid = threadIdx.x;
    if ((tid & 63) == 0) red[tid >> 6] = s;
    __syncthreads();
    if (tid == 0) *partial_slot = (red[0] + red[1]) + (red[2] + red[3]);
}

// ---------------- erode body (aux role) --------------------------------------
__device__ __forceinline__ void erode_body(const float* xP, const float* xG,
                                           const float4* __restrict__ PM,
                                           float* __restrict__ yP,
                                           float* __restrict__ yG, int lin) {
    float a, bm, c4, d4;
    pm_reduce(PM, a, bm, c4, d4);
    const float invP = rcpf(a + 1e-8f);
    const float invG = rcpf(bm + 1e-8f);
    const int T = lin * 256 + threadIdx.x;  // 2048 blocks cover NPIX/4
    int idx = T * 4;
    int i = idx & (HW - 1);
    int y = i >> 9;
    int c = i & (W - 1);
    float4 ctr;
    float t[4], o[4];
    cross4(xP, idx, y, c, ctr, t);
#pragma unroll
    for (int k = 0; k < 4; k++) o[k] = sig_er(t[k] * invP);
    *(float4*)(yP + idx) = make_float4(o[0], o[1], o[2], o[3]);
    cross4(xG, idx, y, c, ctr, t);
#pragma unroll
    for (int k = 0; k < 4; k++) o[k] = sig_er(t[k] * invG);
    *(float4*)(yG + idx) = make_float4(o[0], o[1], o[2], o[3]);
}

// ---------------- mega kernel ------------------------------------------------
// z<8: one cp level (b = z). CPMODE 0: M = raw max (PM.z/.w, level 0);
// CPMODE 1: M = ymax = sig_er(tmax*rcp(tmax+1e-8)) from PM.x/.y (levels 1,2).
// z 8..9: AUX role — 0: erode stage (2048 blocks, 4px/thread);
//                    1: dil levels 0+1 (2*1024 blocks); 2: none.
template <int CPMODE, int AUX>
__global__ __launch_bounds__(256, 4) void mega_kernel(
    const float* xP, const float* xG,            // cp inputs (this level)
    const float4* __restrict__ PMc,              // PM for cp M values
    const float4* PMe,                           // PM for erode stage
    const float* eP, const float* eG,            // erode inputs
    float* __restrict__ yP, float* __restrict__ yG,  // erode outputs
    const __half* __restrict__ dil_cp,           // dil input planes (8 planes)
    float* __restrict__ PS,                      // dil partials base
    __half* __restrict__ cp_out) {               // 4 cp planes out
    const int z = blockIdx.z;
    if (z >= 8) {
        if constexpr (AUX == 0) {
            int lin = (z - 8) * 1024 + blockIdx.y * 32 + blockIdx.x;
            erode_body(eP, eG, PMe, yP, yG, lin);
        } else if constexpr (AUX == 1) {
            int grp = z - 8;  // dil level 0 or 1
            int r = blockIdx.y * 32 + blockIdx.x;
            dil_body(dil_cp + (size_t)(4 * grp) * NPIX, r, PS + grp * NBD + r);
        }
        return;
    }
    // ----- cp part -----
    float MP, MG;
    {
        float a, bm, c4, d4;
        pm_reduce(PMc, a, bm, c4, d4);
        if constexpr (CPMODE == 0) {
            MP = c4; MG = d4;  // raw maxes
        } else {
            MP = sig_er(a * rcpf(a + 1e-8f));    // ymax closed form
            MG = sig_er(bm * rcpf(bm + 1e-8f));
        }
    }
    __syncthreads();  // pm_reduce used LDS; win reuses it below? (separate arrays)

    __shared__ float win[2][21][48];
    const int b = z;
    const int oy0 = blockIdx.y * 16, ox0 = blockIdx.x * 16;
    const bool edge = (blockIdx.x == 0) | (blockIdx.x == (W / 16 - 1)) |
                      (blockIdx.y == 0) | (blockIdx.y == (H / 16 - 1));
    const int tid = threadIdx.x;
    const int ty = tid >> 4, tx = tid & 15;
    const int o = b * HW + (oy0 + ty) * W + (ox0 + tx);

    if (!edge) {
        const float* pb = xP + b * HW + (oy0 - 3) * W + (ox0 - 3);
        const float* gb = xG + b * HW + (oy0 - 3) * W + (ox0 - 3);
        for (int i = tid; i < 21 * 21; i += 256) {
            int r = i / 21, c = i % 21;
            win[0][r][c] = pb[r * W + c];
            win[1][r][c] = gb[r * W + c];
        }
        __syncthreads();
        const float cmP[6] = {fmaf(7.0f * MP, CC, -CC),  fmaf(9.0f * MP, CC, -CC),
                              fmaf(10.0f * MP, CC, -CC), fmaf(11.0f * MP, CC, -CC),
                              fmaf(13.0f * MP, CC, -CC), fmaf(16.0f * MP, CC, -CC)};
        const float cmG[6] = {fmaf(7.0f * MG, CC, -CC),  fmaf(9.0f * MG, CC, -CC),
                              fmaf(10.0f * MG, CC, -CC), fmaf(11.0f * MG, CC, -CC),
                              fmaf(13.0f * MG, CC, -CC), fmaf(16.0f * MG, CC, -CC)};
        float sPd, sPc, sGd, sGc;
        NC a = sweep<48>(&win[0][ty][tx]);
        ssum_from_nc<true>(a, cmP, sPd, sPc);
        NC g = sweep<48>(&win[1][ty][tx]);
        ssum_from_nc<true>(g, cmG, sGd, sGc);
        cp_out[0 * NPIX + o] = __float2half(sig_cp(a.v * sPd));
        cp_out[1 * NPIX + o] = __float2half(sig_cp(g.v * sGd));
        cp_out[2 * NPIX + o] = __float2half(sig_cp((MP - a.v) * sPc));
        cp_out[3 * NPIX + o] = __float2half(sig_cp((MG - g.v) * sGc));
    } else {
        const float* pb = xP + b * HW;
        const float* gb = xG + b * HW;
        // phase A: direct planes
        for (int i = tid; i < 21 * 21; i += 256) {
            int r = i / 21, c = i % 21;
            int pr = oy0 - 2 + r;  // padded coords (0..513 valid)
            int pc = ox0 - 2 + c;
            float vP, vG;
            if (pr < 0 || pr > H + 1 || pc < 0 || pc > W + 1) {
                vP = vG = 0.0f;  // conv zero-pad
            } else if (pr == 0 || pr == H + 1 || pc == 0 || pc == W + 1) {
                vP = vG = 1.0f;  // image 1-pad
            } else {
                vP = pb[(pr - 1) * W + (pc - 1)];
                vG = gb[(pr - 1) * W + (pc - 1)];
            }
            win[0][r][c] = vP; win[1][r][c] = vG;
        }
        __syncthreads();
        float sPd, sPc, sGd, sGc, junk, vPd, vGd;
        NC a = sweep<48>(&win[0][ty][tx]);
        ssum_from_nc<false>(a, nullptr, sPd, junk);  vPd = a.v;
        NC g = sweep<48>(&win[1][ty][tx]);
        ssum_from_nc<false>(g, nullptr, sGd, junk);  vGd = g.v;
        cp_out[0 * NPIX + o] = __float2half(sig_cp(vPd * sPd));
        cp_out[1 * NPIX + o] = __float2half(sig_cp(vGd * sGd));
        __syncthreads();  // all reads of direct planes done
        // phase B: complement planes
        for (int i = tid; i < 21 * 21; i += 256) {
            int r = i / 21, c = i % 21;
            int pr = oy0 - 2 + r;
            int pc = ox0 - 2 + c;
            float vP, vG;
            if (pr < 0 || pr > H + 1 || pc < 0 || pc > W + 1) {
                vP = vG = 0.0f;
            } else if (pr == 0 || pr == H + 1 || pc == 0 || pc == W + 1) {
                vP = vG = 1.0f;
            } else {
                vP = MP - pb[(pr - 1) * W + (pc - 1)];
                vG = MG - gb[(pr - 1) * W + (pc - 1)];
            }
            win[0][r][c] = vP; win[1][r][c] = vG;
        }
        __syncthreads();
        NC ac = sweep<48>(&win[0][ty][tx]);
        ssum_from_nc<false>(ac, nullptr, sPc, junk);
        NC gc = sweep<48>(&win[1][ty][tx]);
        ssum_from_nc<false>(gc, nullptr, sGc, junk);
        cp_out[2 * NPIX + o] = __float2half(sig_cp(ac.v * sPc));
        cp_out[3 * NPIX + o] = __float2half(sig_cp(gc.v * sGc));
    }
}

// ---------------- standalone dil (last level / fallback) ---------------------
__global__ __launch_bounds__(256) void dil_diff2_kernel(
    const __half* __restrict__ cp, float* __restrict__ partial) {
    dil_body(cp, blockIdx.x, partial + blockIdx.x);
}

// ---------------- erosion: cross-conv max pass -> float4 partial/block -------
__global__ __launch_bounds__(256) void cross_max_both_kernel(
    const float* __restrict__ xP, const float* __restrict__ xG,
    float4* __restrict__ partial) {
    float mtP = 0, mtG = 0, mrP = 0, mrG = 0;
    for (int T = blockIdx.x * 256 + threadIdx.x; T < NPIX / 4; T += NB1 * 256) {
        int idx = T * 4;
        int i = idx & (HW - 1);
        int y = i >> 9;
        int c = i & (W - 1);
        float4 ctr;
        float t[4];
        cross4(xP, idx, y, c, ctr, t);
        mtP = fmaxf(mtP, fmaxf(fmaxf(t[0], t[1]), fmaxf(t[2], t[3])));
        mrP = fmaxf(mrP, fmaxf(fmaxf(ctr.x, ctr.y), fmaxf(ctr.z, ctr.w)));
        cross4(xG, idx, y, c, ctr, t);
        mtG = fmaxf(mtG, fmaxf(fmaxf(t[0], t[1]), fmaxf(t[2], t[3])));
        mrG = fmaxf(mrG, fmaxf(fmaxf(ctr.x, ctr.y), fmaxf(ctr.z, ctr.w)));
    }
    mtP = wave_max(mtP); mtG = wave_max(mtG);
    mrP = wave_max(mrP); mrG = wave_max(mrG);
    __shared__ float red[4][4];
    int tid = threadIdx.x;
    if ((tid & 63) == 0) {
        int w = tid >> 6;
        red[w][0] = mtP; red[w][1] = mtG; red[w][2] = mrP; red[w][3] = mrG;
    }
    __syncthreads();
    if (tid == 0) {
        float4 r;
        r.x = fmaxf(fmaxf(red[0][0], red[1][0]), fmaxf(red[2][0], red[3][0]));
        r.y = fmaxf(fmaxf(red[0][1], red[1][1]), fmaxf(red[2][1], red[3][1]));
        r.z = fmaxf(fmaxf(red[0][2], red[1][2]), fmaxf(red[2][2], red[3][2]));
        r.w = fmaxf(fmaxf(red[0][3], red[1][3]), fmaxf(red[2][3], red[3][3]));
        partial[blockIdx.x] = r;
    }
}

// ---------------- final: sum 3*NBD partials, /B ------------------------------
__global__ __launch_bounds__(1024) void finalize_kernel(
    const float* __restrict__ PS, float* out) {
    int t = threadIdx.x;
    float s = PS[t] + PS[t + NBD] + PS[t + 2 * NBD];
    s = wave_sum(s);
    __shared__ float red[16];
    if ((t & 63) == 0) red[t >> 6] = s;
    __syncthreads();
    if (t == 0) {
        float tot = 0.0f;
#pragma unroll
        for (int i = 0; i < 16; i++) tot += red[i];
        out[0] = tot * (1.0f / (float)B);
    }
}

// ---------------- launch -----------------------------------------------------
extern "C" void kernel_launch(void* const* d_in, const int* in_sizes, int n_in,
                              void* d_out, int out_size, void* d_ws, size_t ws_size,
                              hipStream_t stream) {
    (void)in_sizes; (void)n_in; (void)out_size;
    const float* pred = (const float*)d_in[0];
    const float* gt   = (const float*)d_in[1];
    float* out = (float*)d_out;

    // ws (floats): PM1[4*NB1] | PM2[4*NB1] | PS[3*NBD] | P1,G1,P2,G2 | CP (f16)
    float* Sf  = (float*)d_ws;
    float4* PM1 = (float4*)Sf;
    float4* PM2 = PM1 + NB1;
    float* PS = (float*)(PM2 + NB1);
    float* P1 = PS + 3 * NBD;
    float* G1 = P1 + NPIX;
    float* P2 = G1 + NPIX;
    float* G2 = P2 + NPIX;
    __half* CP = (__half*)(G2 + NPIX);

    // merged path needs 12 f16 CP planes (48MB); fallback needs 4
    const size_t base_b = (size_t)(8 * NB1 + 3 * NBD) * 4 + (size_t)4 * NPIX * 4;
    const bool merged = ws_size >= base_b + (size_t)12 * NPIX * 2;

    const dim3 b1(256), g1(NB1);
    const dim3 gM(32, 32, 10);  // z<8 cp, z 8..9 aux
    const dim3 gC(32, 32, 8);   // cp only

    if (merged) {
        __half* CP0 = CP;
        __half* CP1 = CP + (size_t)4 * NPIX;
        __half* CP2 = CP + (size_t)8 * NPIX;
        cross_max_both_kernel<<<g1, b1, 0, stream>>>(pred, gt, PM1);
        // cp level0 (M = raw max from PM1) + erode1 (PM1) -> P1,G1
        mega_kernel<0, 0><<<gM, b1, 0, stream>>>(
            pred, gt, PM1, PM1, pred, gt, P1, G1, nullptr, nullptr, CP0);
        cross_max_both_kernel<<<g1, b1, 0, stream>>>(P1, G1, PM2);
        // cp level1 (M = ymax1 from PM1) + erode2 (PM2) -> P2,G2
        mega_kernel<1, 0><<<gM, b1, 0, stream>>>(
            P1, G1, PM1, PM2, P1, G1, P2, G2, nullptr, nullptr, CP1);
        // cp level2 (M = ymax2 from PM2) + dil levels 0,1
        mega_kernel<1, 1><<<gM, b1, 0, stream>>>(
            P2, G2, PM2, nullptr, nullptr, nullptr, nullptr, nullptr, CP, PS, CP2);
        dil_diff2_kernel<<<dim3(NBD), b1, 0, stream>>>(CP2, PS + 2 * NBD);
    } else {
        // fallback: 4 CP planes, dil after each level
        cross_max_both_kernel<<<g1, b1, 0, stream>>>(pred, gt, PM1);
        mega_kernel<0, 0><<<gM, b1, 0, stream>>>(
            pred, gt, PM1, PM1, pred, gt, P1, G1, nullptr, nullptr, CP);
        dil_diff2_kernel<<<dim3(NBD), b1, 0, stream>>>(CP, PS);
        cross_max_both_kernel<<<g1, b1, 0, stream>>>(P1, G1, PM2);
        mega_kernel<1, 0><<<gM, b1, 0, stream>>>(
            P1, G1, PM1, PM2, P1, G1, P2, G2, nullptr, nullptr, CP);
        dil_diff2_kernel<<<dim3(NBD), b1, 0, stream>>>(CP, PS + NBD);
        mega_kernel<1, 2><<<gC, b1, 0, stream>>>(
            P2, G2, PM2, nullptr, nullptr, nullptr, nullptr, nullptr, nullptr,
            nullptr, CP);
        dil_diff2_kernel<<<dim3(NBD), b1, 0, stream>>>(CP, PS + 2 * NBD);
    }

    finalize_kernel<<<1, 1024, 0, stream>>>(PS, out);
}

// Round 12
// 350.968 us; speedup vs baseline: 1.0483x; 1.0483x over previous
//
#include <hip/hip_runtime.h>
#include <hip/hip_fp16.h>
#include <cstdint>

// Problem constants (setup_inputs: B=8, H=W=512, num_erosions=2)
static constexpr int B = 8;
static constexpr int H = 512;
static constexpr int W = 512;
static constexpr int HW = H * W;
static constexpr int NPIX = B * HW;
static constexpr int NB1 = 1024;  // blocks for cross_max partials
static constexpr int NBD = 1024;  // blocks per dil_diff level

// 10*log2(e): sigmoid(10*z) = 1/(1+2^(-CC*z))
static constexpr float CC = 14.4269504088896f;

// ---------------- helpers ----------------------------------------------------
// Raw v_exp_f32/v_rcp_f32 via builtins (R4: ocml exp = ~12 inst). No
// multi-block atomics (R5: same-line atomic chain serializes device-wide).
// Straight-line sigmoids (R3: wave-vote branches killed ILP). R11's mega
// co-scheduling regressed (VGPR 48->64, occupancy 46->35%) — reverted to R10.
__device__ __forceinline__ float rcpf(float x) { return __builtin_amdgcn_rcpf(x); }
__device__ __forceinline__ float exp2f_n(float x) { return __builtin_amdgcn_exp2f(x); }
__device__ __forceinline__ float endsig(float nc) {
    return rcpf(1.0f + exp2f_n(fmaf(nc, CC, -CC)));
}
__device__ __forceinline__ float sig_cp(float x) {  // sigmoid(10(x-0.5))
    return rcpf(1.0f + exp2f_n(fmaf(x, -CC, 0.5f * CC)));
}
__device__ __forceinline__ float sig_er(float r) {  // sigmoid(10(r-0.7))
    return rcpf(1.0f + exp2f_n(fmaf(r, -CC, 0.7f * CC)));
}
// Shared-exp complement pair (R12): u_d=2^(CC*nc-CC), u_c=2^(cm-CC*nc),
// u_d*u_c = 2^(cm-CC) uniform. With m=(cm-CC)/2, s=2^m, w=2^(CC*nc-CC-m):
// direct = rcp(1+w*s), comp = w*rcp(w+s). One exp/pair instead of two.
// w*s exact (s = power of 2); INF/0 saturations land on correct 0/1.
__device__ __forceinline__ void pair_term(float nc, float negA, float s2m,
                                          float& sd, float& sc) {
    float w = exp2f_n(fmaf(nc, CC, negA));  // negA = -(CC + m)
    sd += rcpf(fmaf(w, s2m, 1.0f));
    sc += w * rcpf(w + s2m);
}
__device__ __forceinline__ float wave_max(float m) {
#pragma unroll
    for (int o = 32; o > 0; o >>= 1) m = fmaxf(m, __shfl_down(m, o, 64));
    return m;
}
__device__ __forceinline__ float wave_sum(float s) {
#pragma unroll
    for (int o = 32; o > 0; o >>= 1) s += __shfl_down(s, o, 64);
    return s;
}

// ---------------- row-sweep mask conv sums (unchanged) -----------------------
struct NC {
    float n3[8], n4[8], n5[8], n6[7];
    float v;  // center value w[3][3]
};

template <int STRIDE>
__device__ __forceinline__ NC sweep(const float* rp) {
    NC o;
    float r2s, r3s, r4s;
    float cen0, cen1, cen2, cen3, cen4, cen5, cen6, cen7, cen8;
    {   // win row 0 = K6 row 0
        float c0 = rp[0], c1 = rp[1], c2 = rp[2], c3 = rp[3], c4 = rp[4], c5 = rp[5];
        float c45 = c4 + c5, c01 = c0 + c1;
        float S6 = (c01 + (c2 + c3)) + c45;
        o.n6[0] = c45; o.n6[1] = c01; o.n6[2] = S6; o.n6[3] = S6;
        o.n6[4] = S6;  o.n6[5] = S6;  o.n6[6] = S6;
    }
    rp += STRIDE;
    {   // win row 1 = K6 r1, K5 r0, K4 r0
        float c0 = rp[0], c1 = rp[1], c2 = rp[2], c3 = rp[3], c4 = rp[4], c5 = rp[5];
        float c45 = c4 + c5, c12 = c1 + c2, c34 = c3 + c4;
        float S4 = c12 + c34, S5 = S4 + c5;
        float c15 = c1 + c5, c05 = c0 + c5, c14 = c1 + c4;
        o.n6[0] += c5;  o.n6[1] += c0;  o.n6[2] += c05; o.n6[3] += c05;
        o.n6[4] += c0;  o.n6[5] += c5;  o.n6[6] += c05;
        o.n5[0] = c45; o.n5[1] = c12; o.n5[2] = S5; o.n5[3] = S5;
        o.n5[4] = S5;  o.n5[5] = S5;  o.n5[6] = S5; o.n5[7] = c15;
        o.n4[0] = c34; o.n4[1] = c12; o.n4[2] = S4; o.n4[3] = S4;
        o.n4[4] = c14; o.n4[5] = S4;  o.n4[6] = S4; o.n4[7] = S4;
    }
    rp += STRIDE;
    {   // win row 2 = K6 r2, K5 r1, K4 r1, K3 r0
        float c0 = rp[0], c1 = rp[1], c2 = rp[2], c3 = rp[3], c4 = rp[4], c5 = rp[5];
        float c05 = c0 + c5, c15 = c1 + c5, c14 = c1 + c4;
        r2s = (c2 + c3) + c4;
        cen0 = c2; cen1 = c3; cen2 = c4;
        o.n6[0] += c5;  o.n6[1] += c0;  o.n6[2] += c0;  o.n6[3] += c5;
        o.n6[4] += c0;  o.n6[5] += c5;  o.n6[6] += c05;
        o.n5[0] += c5;  o.n5[1] += c1;  o.n5[2] += c15; o.n5[3] += c15;
        o.n5[4] += c1;  o.n5[5] += c5;  o.n5[6] += c15; o.n5[7] += c15;
        o.n4[0] += c4;  o.n4[1] += c1;  o.n4[2] += c14; o.n4[3] += c14;
        o.n4[4] += c14; o.n4[5] += c4;  o.n4[6] += c14; o.n4[7] += c1;
    }
    rp += STRIDE;
    {   // win row 3 = K6 r3, K5 r2, K4 r2, K3 r1 (center row)
        float c0 = rp[0], c1 = rp[1], c2 = rp[2], c3 = rp[3], c4 = rp[4], c5 = rp[5];
        float c05 = c0 + c5, c15 = c1 + c5, c14 = c1 + c4;
        r3s = (c2 + c3) + c4;
        cen3 = c2; cen4 = c3; cen5 = c4;
        o.v = c3;
        o.n6[0] += c5;  o.n6[1] += c0;  o.n6[2] += c0;  o.n6[3] += c5;
        o.n6[4] += c0;  o.n6[5] += c5;  o.n6[6] += c05;
        o.n5[0] += c5;  o.n5[1] += c1;  o.n5[2] += c1;  o.n5[3] += c5;
        o.n5[4] += c1;  o.n5[5] += c5;  o.n5[6] += c15; o.n5[7] += c15;
        o.n4[0] += c14; o.n4[1] += c14; o.n4[2] += c4;  o.n4[3] += c1;
        o.n4[4] += c14; o.n4[5] += c4;  o.n4[6] += c14; o.n4[7] += c1;
    }
    rp += STRIDE;
    {   // win row 4 = K6 r4, K5 r3, K4 r3, K3 r2
        float c0 = rp[0], c1 = rp[1], c2 = rp[2], c3 = rp[3], c4 = rp[4], c5 = rp[5];
        float c05 = c0 + c5, c15 = c1 + c5, c12 = c1 + c2, c34 = c3 + c4;
        float S4 = c12 + c34, c14 = c1 + c4;
        r4s = (c2 + c3) + c4;
        cen6 = c2; cen7 = c3; cen8 = c4;
        o.n6[0] += c05; o.n6[1] += c05; o.n6[2] += c0;  o.n6[3] += c5;
        o.n6[4] += c0;  o.n6[5] += c5;  o.n6[6] += c05;
        o.n5[0] += c15; o.n5[1] += c15; o.n5[2] += c1;  o.n5[3] += c5;
        o.n5[4] += c1;  o.n5[5] += c5;  o.n5[6] += c15; o.n5[7] += c15;
        o.n4[0] += S4;  o.n4[1] += S4;  o.n4[2] += c34; o.n4[3] += c12;
        o.n4[4] += S4;  o.n4[5] += S4;  o.n4[6] += c14; o.n4[7] += S4;
    }
    rp += STRIDE;
    {   // win row 5 = K6 r5, K5 r4
        float c0 = rp[0], c1 = rp[1], c2 = rp[2], c3 = rp[3], c4 = rp[4], c5 = rp[5];
        float c45 = c4 + c5, c12 = c1 + c2;
        float t = c3 + c45, S5 = c12 + t, S6 = S5 + c0;
        float c01 = c0 + c1, c05 = c0 + c5, c15 = c1 + c5;
        o.n6[0] += S6;  o.n6[1] += S6;  o.n6[2] += c01; o.n6[3] += c45;
        o.n6[4] += S6;  o.n6[5] += S6;  o.n6[6] += c05;
        o.n5[0] += S5;  o.n5[1] += S5;  o.n5[2] += c12; o.n5[3] += c45;
        o.n5[4] += S5;  o.n5[5] += S5;  o.n5[6] += c15; o.n5[7] += S5;
    }
    // K3: all 8 masks = S33 - center - one distinct cell
    float S33 = (r2s + r3s) + r4s;
    float T = S33 - cen4;
    o.n3[0] = T - cen3; o.n3[1] = T - cen7; o.n3[2] = T - cen5; o.n3[3] = T - cen1;
    o.n3[4] = T - cen0; o.n3[5] = T - cen6; o.n3[6] = T - cen8; o.n3[7] = T - cen2;
    return o;
}

// class index per mask into per-class constants; counts {7,9,10,11,13,16}
__constant__ __device__ const int CI4[8] = {1, 1, 1, 1, 2, 2, 2, 2};
__constant__ __device__ const int CI5[8] = {3, 3, 3, 3, 4, 4, 4, 4};
__constant__ __device__ const int CI6[7] = {4, 4, 4, 4, 5, 5, 5};

// PAIR=true: negA[6] = -(CC+m_c), s2m[6] = 2^m_c (shared-exp pairs).
// PAIR=false: plain endsig on direct only (edge blocks).
template <bool PAIR>
__device__ __forceinline__ void ssum_from_nc(const NC& a, const float* negA,
                                             const float* s2m, float& sD,
                                             float& sC) {
    float sd = 0.0f, sc = 0.0f;
#pragma unroll
    for (int k = 0; k < 8; k++) {
        if constexpr (PAIR) pair_term(a.n3[k], negA[0], s2m[0], sd, sc);
        else sd += endsig(a.n3[k]);
    }
#pragma unroll
    for (int k = 0; k < 8; k++) {
        if constexpr (PAIR) pair_term(a.n4[k], negA[CI4[k]], s2m[CI4[k]], sd, sc);
        else sd += endsig(a.n4[k]);
    }
#pragma unroll
    for (int k = 0; k < 8; k++) {
        if constexpr (PAIR) pair_term(a.n5[k], negA[CI5[k]], s2m[CI5[k]], sd, sc);
        else sd += endsig(a.n5[k]);
    }
#pragma unroll
    for (int k = 0; k < 7; k++) {
        if constexpr (PAIR) pair_term(a.n6[k], negA[CI6[k]], s2m[CI6[k]], sd, sc);
        else sd += endsig(a.n6[k]);
    }
    sD = sd;
    sC = sc;
}

// build per-class pair constants from M: cm = CC*(cnt*M-1), m = (cm-CC)/2
__device__ __forceinline__ void build_pair_consts(float M, float* negA,
                                                  float* s2m) {
    const float cntf[6] = {7.0f, 9.0f, 10.0f, 11.0f, 13.0f, 16.0f};
#pragma unroll
    for (int c = 0; c < 6; c++) {
        float cm = fmaf(cntf[c] * M, CC, -CC);
        float m = 0.5f * (cm - CC);
        negA[c] = -(CC + m);
        s2m[c] = exp2f_n(m);
    }
}

// ---------------- cp_quad: multi-level (R10 structure) -----------------------
// z-slice -> (lvl = lvl_base + z>>3, b = z&7). lvl selects input pair + M
// slots; planes at cp + 4*(lvl-plane_lvl0)*NPIX. One merged dispatch = one
// residency tail (R10: VALUBusy 84.6%).
__global__ __launch_bounds__(256, 4) void cp_quad_kernel(
    const float* __restrict__ x0P, const float* __restrict__ x0G,
    const float* __restrict__ x1P, const float* __restrict__ x1G,
    const float* __restrict__ x2P, const float* __restrict__ x2G,
    const float* __restrict__ S, int lvl_base, int plane_lvl0,
    __half* __restrict__ cp) {
    __shared__ float win[2][21][48];
    const int lvl = lvl_base + (blockIdx.z >> 3);
    const int b = blockIdx.z & 7;
    const float* xP = (lvl == 0) ? x0P : (lvl == 1) ? x1P : x2P;
    const float* xG = (lvl == 0) ? x0G : (lvl == 1) ? x1G : x2G;
    const float MP = S[lvl], MG = S[3 + lvl];
    __half* cpb = cp + (size_t)(4 * (lvl - plane_lvl0)) * NPIX;

    const int oy0 = blockIdx.y * 16, ox0 = blockIdx.x * 16;
    const bool edge = (blockIdx.x == 0) | (blockIdx.x == (W / 16 - 1)) |
                      (blockIdx.y == 0) | (blockIdx.y == (H / 16 - 1));
    const int tid = threadIdx.y * 16 + threadIdx.x;
    const int ty = threadIdx.y, tx = threadIdx.x;
    const int o = b * HW + (oy0 + ty) * W + (ox0 + tx);

    if (!edge) {
        const float* pb = xP + b * HW + (oy0 - 3) * W + (ox0 - 3);
        const float* gb = xG + b * HW + (oy0 - 3) * W + (ox0 - 3);
        for (int i = tid; i < 21 * 21; i += 256) {
            int r = i / 21, c = i % 21;
            win[0][r][c] = pb[r * W + c];
            win[1][r][c] = gb[r * W + c];
        }
        __syncthreads();
        float negA[6], s2m[6], sPd, sPc, sGd, sGc;
        build_pair_consts(MP, negA, s2m);
        NC a = sweep<48>(&win[0][ty][tx]);
        ssum_from_nc<true>(a, negA, s2m, sPd, sPc);
        build_pair_consts(MG, negA, s2m);
        NC g = sweep<48>(&win[1][ty][tx]);
        ssum_from_nc<true>(g, negA, s2m, sGd, sGc);
        cpb[0 * NPIX + o] = __float2half(sig_cp(a.v * sPd));
        cpb[1 * NPIX + o] = __float2half(sig_cp(g.v * sGd));
        cpb[2 * NPIX + o] = __float2half(sig_cp((MP - a.v) * sPc));
        cpb[3 * NPIX + o] = __float2half(sig_cp((MG - g.v) * sGc));
    } else {
        const float* pb = xP + b * HW;
        const float* gb = xG + b * HW;
        // phase A: direct planes
        for (int i = tid; i < 21 * 21; i += 256) {
            int r = i / 21, c = i % 21;
            int pr = oy0 - 2 + r;  // padded coords (0..513 valid)
            int pc = ox0 - 2 + c;
            float vP, vG;
            if (pr < 0 || pr > H + 1 || pc < 0 || pc > W + 1) {
                vP = vG = 0.0f;  // conv zero-pad
            } else if (pr == 0 || pr == H + 1 || pc == 0 || pc == W + 1) {
                vP = vG = 1.0f;  // image 1-pad
            } else {
                vP = pb[(pr - 1) * W + (pc - 1)];
                vG = gb[(pr - 1) * W + (pc - 1)];
            }
            win[0][r][c] = vP; win[1][r][c] = vG;
        }
        __syncthreads();
        float sPd, sPc, sGd, sGc, junk, vPd, vGd;
        NC a = sweep<48>(&win[0][ty][tx]);
        ssum_from_nc<false>(a, nullptr, nullptr, sPd, junk);  vPd = a.v;
        NC g = sweep<48>(&win[1][ty][tx]);
        ssum_from_nc<false>(g, nullptr, nullptr, sGd, junk);  vGd = g.v;
        cpb[0 * NPIX + o] = __float2half(sig_cp(vPd * sPd));
        cpb[1 * NPIX + o] = __float2half(sig_cp(vGd * sGd));
        __syncthreads();  // all reads of direct planes done
        // phase B: complement planes
        for (int i = tid; i < 21 * 21; i += 256) {
            int r = i / 21, c = i % 21;
            int pr = oy0 - 2 + r;
            int pc = ox0 - 2 + c;
            float vP, vG;
            if (pr < 0 || pr > H + 1 || pc < 0 || pc > W + 1) {
                vP = vG = 0.0f;
            } else if (pr == 0 || pr == H + 1 || pc == 0 || pc == W + 1) {
                vP = vG = 1.0f;
            } else {
                vP = MP - pb[(pr - 1) * W + (pc - 1)];
                vG = MG - gb[(pr - 1) * W + (pc - 1)];
            }
            win[0][r][c] = vP; win[1][r][c] = vG;
        }
        __syncthreads();
        NC ac = sweep<48>(&win[0][ty][tx]);
        ssum_from_nc<false>(ac, nullptr, nullptr, sPc, junk);
        NC gc = sweep<48>(&win[1][ty][tx]);
        ssum_from_nc<false>(gc, nullptr, nullptr, sGc, junk);
        cpb[2 * NPIX + o] = __float2half(sig_cp(ac.v * sPc));
        cpb[3 * NPIX + o] = __float2half(sig_cp(gc.v * sGc));
    }
}

// ---------------- dil_diff: 8 rows/thread, f16 input, multi-level ------------
__device__ __forceinline__ void dil_rows10(const __half* __restrict__ p,
                                           int base, int y0, int x,
                                           float rs[10]) {
#pragma unroll
    for (int j = 0; j < 10; j++) {
        int yy = y0 - 1 + j;
        float l = 0, m = 0, r = 0;
        if (yy >= 0 && yy < H) {  // wave-uniform
            int rb = base + yy * W;
            m = __half2float(p[rb + x]);
            int xl = x > 0 ? x - 1 : 0;
            int xr = x < W - 1 ? x + 1 : W - 1;
            float lv = __half2float(p[rb + xl]);
            float rv = __half2float(p[rb + xr]);
            l = x > 0 ? lv : 0.0f;
            r = x < W - 1 ? rv : 0.0f;
        }
        rs[j] = (l + m) + r;
    }
}

__global__ __launch_bounds__(256) void dil_diff2_kernel(
    const __half* __restrict__ cp, float* __restrict__ partial) {
    const int plane_grp = blockIdx.x >> 10;  // NBD=1024 blocks per level
    const int r = blockIdx.x & (NBD - 1);
    const __half* cpb = cp + (size_t)(4 * plane_grp) * NPIX;
    const int T = r * 256 + threadIdx.x;
    const int x = T & (W - 1);
    const int g = T >> 9;
    const int y0 = (g & 63) << 3;  // 64 rowgroups of 8 rows
    const int b = g >> 6;
    const int base = b * HW;

    float rs0[10], rs1[10], rs2[10], rs3[10];
    dil_rows10(cpb + 0 * NPIX, base, y0, x, rs0);
    dil_rows10(cpb + 1 * NPIX, base, y0, x, rs1);
    dil_rows10(cpb + 2 * NPIX, base, y0, x, rs2);
    dil_rows10(cpb + 3 * NPIX, base, y0, x, rs3);

    float s = 0.0f;
#pragma unroll
    for (int i = 0; i < 8; i++) {
        float s0 = (rs0[i] + rs0[i + 1]) + rs0[i + 2];
        float s1 = (rs1[i] + rs1[i + 1]) + rs1[i + 2];
        float s2 = (rs2[i] + rs2[i + 1]) + rs2[i + 2];
        float s3 = (rs3[i] + rs3[i + 1]) + rs3[i + 2];
        float d1 = fminf(s0, 1.0f) - fminf(s1, 1.0f);
        float d2 = fminf(s2, 1.0f) - fminf(s3, 1.0f);
        s += fmaf(d1, d1, d2 * d2);
    }
    s = wave_sum(s);
    __shared__ float red[4];
    int tid = threadIdx.x;
    if ((tid & 63) == 0) red[tid >> 6] = s;
    __syncthreads();
    if (tid == 0) partial[blockIdx.x] = (red[0] + red[1]) + (red[2] + red[3]);
}

// ---------------- cross-conv 4px/thread helper -------------------------------
__device__ __forceinline__ void cross4(const float* __restrict__ xp, int idx,
                                       int y, int c, float4& ctr, float t[4]) {
    const float4* v = (const float4*)(xp + idx);
    ctr = v[0];
    float4 up = (y > 0) ? *(const float4*)(xp + idx - W)
                        : make_float4(0, 0, 0, 0);
    float4 dn = (y < H - 1) ? *(const float4*)(xp + idx + W)
                            : make_float4(0, 0, 0, 0);
    float lf = (c > 0) ? xp[idx - 1] : 0.0f;
    float rt = (c < W - 4) ? xp[idx + 4] : 0.0f;
    t[0] = (up.x + dn.x) + (lf + ctr.y);
    t[1] = (up.y + dn.y) + (ctr.x + ctr.z);
    t[2] = (up.z + dn.z) + (ctr.y + ctr.w);
    t[3] = (up.w + dn.w) + (ctr.z + rt);
}

// ---------------- erosion: cross-conv max pass -> float4 partial/block -------
__global__ __launch_bounds__(256) void cross_max_both_kernel(
    const float* __restrict__ xP, const float* __restrict__ xG,
    float4* __restrict__ partial) {
    float mtP = 0, mtG = 0, mrP = 0, mrG = 0;
    for (int T = blockIdx.x * 256 + threadIdx.x; T < NPIX / 4; T += NB1 * 256) {
        int idx = T * 4;
        int i = idx & (HW - 1);
        int y = i >> 9;
        int c = i & (W - 1);
        float4 ctr;
        float t[4];
        cross4(xP, idx, y, c, ctr, t);
        mtP = fmaxf(mtP, fmaxf(fmaxf(t[0], t[1]), fmaxf(t[2], t[3])));
        mrP = fmaxf(mrP, fmaxf(fmaxf(ctr.x, ctr.y), fmaxf(ctr.z, ctr.w)));
        cross4(xG, idx, y, c, ctr, t);
        mtG = fmaxf(mtG, fmaxf(fmaxf(t[0], t[1]), fmaxf(t[2], t[3])));
        mrG = fmaxf(mrG, fmaxf(fmaxf(ctr.x, ctr.y), fmaxf(ctr.z, ctr.w)));
    }
    mtP = wave_max(mtP); mtG = wave_max(mtG);
    mrP = wave_max(mrP); mrG = wave_max(mrG);
    __shared__ float red[4][4];
    int tid = threadIdx.x;
    if ((tid & 63) == 0) {
        int w = tid >> 6;
        red[w][0] = mtP; red[w][1] = mtG; red[w][2] = mrP; red[w][3] = mrG;
    }
    __syncthreads();
    if (tid == 0) {
        float4 r;
        r.x = fmaxf(fmaxf(red[0][0], red[1][0]), fmaxf(red[2][0], red[3][0]));
        r.y = fmaxf(fmaxf(red[0][1], red[1][1]), fmaxf(red[2][1], red[3][1]));
        r.z = fmaxf(fmaxf(red[0][2], red[1][2]), fmaxf(red[2][2], red[3][2]));
        r.w = fmaxf(fmaxf(red[0][3], red[1][3]), fmaxf(red[2][3], red[3][3]));
        partial[blockIdx.x] = r;
    }
}

// ---------------- erosion: fused PM-reduce + cross conv + normalize ----------
__global__ __launch_bounds__(256) void erode_both_kernel(
    const float* __restrict__ xP, const float* __restrict__ xG,
    const float4* __restrict__ PM,
    float* __restrict__ yP, float* __restrict__ yG,
    float* ymaxP, float* ymaxG, float* rmaxP, float* rmaxG) {
    // redundant per-block PM reduce (16KB, L2-resident)
    float a = 0, bm = 0, c4 = 0, d4 = 0;
    {
        int t = threadIdx.x;
#pragma unroll
        for (int k = 0; k < NB1 / 256; k++) {
            float4 p = PM[t + k * 256];
            a = fmaxf(a, p.x); bm = fmaxf(bm, p.y);
            c4 = fmaxf(c4, p.z); d4 = fmaxf(d4, p.w);
        }
        a = wave_max(a); bm = wave_max(bm); c4 = wave_max(c4); d4 = wave_max(d4);
        __shared__ float red[4][4];
        if ((t & 63) == 0) {
            int w = t >> 6;
            red[w][0] = a; red[w][1] = bm; red[w][2] = c4; red[w][3] = d4;
        }
        __syncthreads();
        a  = fmaxf(fmaxf(red[0][0], red[1][0]), fmaxf(red[2][0], red[3][0]));
        bm = fmaxf(fmaxf(red[0][1], red[1][1]), fmaxf(red[2][1], red[3][1]));
        c4 = fmaxf(fmaxf(red[0][2], red[1][2]), fmaxf(red[2][2], red[3][2]));
        d4 = fmaxf(fmaxf(red[0][3], red[1][3]), fmaxf(red[2][3], red[3][3]));
    }
    const float tP_max = a, tG_max = bm;
    const float invP = rcpf(tP_max + 1e-8f);
    const float invG = rcpf(tG_max + 1e-8f);

    const int T = blockIdx.x * 256 + threadIdx.x;  // 2048 blocks cover NPIX/4
    if (T < NPIX / 4) {
        int idx = T * 4;
        int i = idx & (HW - 1);
        int y = i >> 9;
        int c = i & (W - 1);
        float4 ctr;
        float t[4], o[4];
        cross4(xP, idx, y, c, ctr, t);
#pragma unroll
        for (int k = 0; k < 4; k++) o[k] = sig_er(t[k] * invP);
        *(float4*)(yP + idx) = make_float4(o[0], o[1], o[2], o[3]);
        cross4(xG, idx, y, c, ctr, t);
#pragma unroll
        for (int k = 0; k < 4; k++) o[k] = sig_er(t[k] * invG);
        *(float4*)(yG + idx) = make_float4(o[0], o[1], o[2], o[3]);
    }
    if (blockIdx.x == 0 && threadIdx.x == 0) {
        *ymaxP = sig_er(tP_max * invP);
        *ymaxG = sig_er(tG_max * invG);
        *rmaxP = c4;
        *rmaxG = d4;
    }
}

// ---------------- final: sum 3*NBD partials, /B ------------------------------
__global__ __launch_bounds__(1024) void finalize_kernel(
    const float* __restrict__ PS, float* out) {
    int t = threadIdx.x;
    float s = PS[t] + PS[t + NBD] + PS[t + 2 * NBD];
    s = wave_sum(s);
    __shared__ float red[16];
    if ((t & 63) == 0) red[t >> 6] = s;
    __syncthreads();
    if (t == 0) {
        float tot = 0.0f;
#pragma unroll
        for (int i = 0; i < 16; i++) tot += red[i];
        out[0] = tot * (1.0f / (float)B);
    }
}

// ---------------- launch -----------------------------------------------------
extern "C" void kernel_launch(void* const* d_in, const int* in_sizes, int n_in,
                              void* d_out, int out_size, void* d_ws, size_t ws_size,
                              hipStream_t stream) {
    (void)in_sizes; (void)n_in; (void)out_size;
    const float* pred = (const float*)d_in[0];
    const float* gt   = (const float*)d_in[1];
    float* out = (float*)d_out;

    // ws (floats): S[64] | PM[4*NB1] | PS[3*NBD] | P1,G1,P2,G2 | CP (f16)
    float* S  = (float*)d_ws;
    float4* PM = (float4*)(S + 64);
    float* PS = S + 64 + 4 * NB1;
    float* P1 = PS + 3 * NBD;
    float* G1 = P1 + NPIX;
    float* P2 = G1 + NPIX;
    float* G2 = P2 + NPIX;
    __half* CP = (__half*)(G2 + NPIX);

    // merged path needs 12 f16 CP planes (48MB); fallback (R9 schedule) needs 4
    const size_t base_b = (size_t)(64 + 4 * NB1 + 3 * NBD) * 4 +
                          (size_t)4 * NPIX * 4;
    const bool merged = ws_size >= base_b + (size_t)12 * NPIX * 2;

    const dim3 b1(256), g1(NB1), gE(NPIX / 4 / 256);
    const dim3 b2(16, 16, 1);

    // erosion chain
    cross_max_both_kernel<<<g1, b1, 0, stream>>>(pred, gt, PM);
    erode_both_kernel<<<gE, b1, 0, stream>>>(pred, gt, PM, P1, G1,
                                             S + 1, S + 4, S + 0, S + 3);
    cross_max_both_kernel<<<g1, b1, 0, stream>>>(P1, G1, PM);
    erode_both_kernel<<<gE, b1, 0, stream>>>(P1, G1, PM, P2, G2,
                                             S + 2, S + 5, S + 12, S + 13);

    if (merged) {
        // all 3 levels in one cp dispatch (one tail) + one dil dispatch
        cp_quad_kernel<<<dim3(W / 16, H / 16, 3 * B), b2, 0, stream>>>(
            pred, gt, P1, G1, P2, G2, S, 0, 0, CP);
        dil_diff2_kernel<<<dim3(3 * NBD), b1, 0, stream>>>(CP, PS);
    } else {
        for (int lvl = 0; lvl < 3; lvl++) {
            cp_quad_kernel<<<dim3(W / 16, H / 16, B), b2, 0, stream>>>(
                pred, gt, P1, G1, P2, G2, S, lvl, lvl, CP);
            dil_diff2_kernel<<<dim3(NBD), b1, 0, stream>>>(CP, PS + lvl * NBD);
        }
    }

    finalize_kernel<<<1, 1024, 0, stream>>>(PS, out);
}

// Round 13
// 349.191 us; speedup vs baseline: 1.0536x; 1.0051x over previous
//
#include <hip/hip_runtime.h>
#include <hip/hip_fp16.h>
#include <cstdint>

// Problem constants (setup_inputs: B=8, H=W=512, num_erosions=2)
static constexpr int B = 8;
static constexpr int H = 512;
static constexpr int W = 512;
static constexpr int HW = H * W;
static constexpr int NPIX = B * HW;
static constexpr int NB1 = 1024;  // blocks for cross_max partials
static constexpr int NBD = 1024;  // blocks per dil_diff level

// 10*log2(e): sigmoid(10*z) = 1/(1+2^(-CC*z))
static constexpr float CC = 14.4269504088896f;

// ---------------- helpers ----------------------------------------------------
// Raw v_exp_f32/v_rcp_f32 via builtins (R4: ocml exp = ~12 inst). No
// multi-block atomics (R5: same-line atomic chain serializes device-wide).
// Straight-line sigmoids (R3: wave-vote branches killed ILP). R11 mega
// co-scheduling regressed (VGPR/occupancy) — R10 structure retained.
// R12: issue dropped 8% with no time change -> cp stall-bound at ~41% occ;
// R13 requests 8 waves/EU residency.
__device__ __forceinline__ float rcpf(float x) { return __builtin_amdgcn_rcpf(x); }
__device__ __forceinline__ float exp2f_n(float x) { return __builtin_amdgcn_exp2f(x); }
__device__ __forceinline__ float endsig(float nc) {
    return rcpf(1.0f + exp2f_n(fmaf(nc, CC, -CC)));
}
__device__ __forceinline__ float sig_cp(float x) {  // sigmoid(10(x-0.5))
    return rcpf(1.0f + exp2f_n(fmaf(x, -CC, 0.5f * CC)));
}
__device__ __forceinline__ float sig_er(float r) {  // sigmoid(10(r-0.7))
    return rcpf(1.0f + exp2f_n(fmaf(r, -CC, 0.7f * CC)));
}
// Shared-exp complement pair (R12): u_d=2^(CC*nc-CC), u_c=2^(cm-CC*nc),
// u_d*u_c = 2^(cm-CC) uniform. With m=(cm-CC)/2, s=2^m, w=2^(CC*nc-CC-m):
// direct = rcp(1+w*s), comp = w*rcp(w+s). One exp/pair instead of two.
__device__ __forceinline__ void pair_term(float nc, float negA, float s2m,
                                          float& sd, float& sc) {
    float w = exp2f_n(fmaf(nc, CC, negA));  // negA = -(CC + m)
    sd += rcpf(fmaf(w, s2m, 1.0f));
    sc += w * rcpf(w + s2m);
}
__device__ __forceinline__ float wave_max(float m) {
#pragma unroll
    for (int o = 32; o > 0; o >>= 1) m = fmaxf(m, __shfl_down(m, o, 64));
    return m;
}
__device__ __forceinline__ float wave_sum(float s) {
#pragma unroll
    for (int o = 32; o > 0; o >>= 1) s += __shfl_down(s, o, 64);
    return s;
}

// ---------------- row-sweep mask conv sums (unchanged) -----------------------
struct NC {
    float n3[8], n4[8], n5[8], n6[7];
    float v;  // center value w[3][3]
};

template <int STRIDE>
__device__ __forceinline__ NC sweep(const float* rp) {
    NC o;
    float r2s, r3s, r4s;
    float cen0, cen1, cen2, cen3, cen4, cen5, cen6, cen7, cen8;
    {   // win row 0 = K6 row 0
        float c0 = rp[0], c1 = rp[1], c2 = rp[2], c3 = rp[3], c4 = rp[4], c5 = rp[5];
        float c45 = c4 + c5, c01 = c0 + c1;
        float S6 = (c01 + (c2 + c3)) + c45;
        o.n6[0] = c45; o.n6[1] = c01; o.n6[2] = S6; o.n6[3] = S6;
        o.n6[4] = S6;  o.n6[5] = S6;  o.n6[6] = S6;
    }
    rp += STRIDE;
    {   // win row 1 = K6 r1, K5 r0, K4 r0
        float c0 = rp[0], c1 = rp[1], c2 = rp[2], c3 = rp[3], c4 = rp[4], c5 = rp[5];
        float c45 = c4 + c5, c12 = c1 + c2, c34 = c3 + c4;
        float S4 = c12 + c34, S5 = S4 + c5;
        float c15 = c1 + c5, c05 = c0 + c5, c14 = c1 + c4;
        o.n6[0] += c5;  o.n6[1] += c0;  o.n6[2] += c05; o.n6[3] += c05;
        o.n6[4] += c0;  o.n6[5] += c5;  o.n6[6] += c05;
        o.n5[0] = c45; o.n5[1] = c12; o.n5[2] = S5; o.n5[3] = S5;
        o.n5[4] = S5;  o.n5[5] = S5;  o.n5[6] = S5; o.n5[7] = c15;
        o.n4[0] = c34; o.n4[1] = c12; o.n4[2] = S4; o.n4[3] = S4;
        o.n4[4] = c14; o.n4[5] = S4;  o.n4[6] = S4; o.n4[7] = S4;
    }
    rp += STRIDE;
    {   // win row 2 = K6 r2, K5 r1, K4 r1, K3 r0
        float c0 = rp[0], c1 = rp[1], c2 = rp[2], c3 = rp[3], c4 = rp[4], c5 = rp[5];
        float c05 = c0 + c5, c15 = c1 + c5, c14 = c1 + c4;
        r2s = (c2 + c3) + c4;
        cen0 = c2; cen1 = c3; cen2 = c4;
        o.n6[0] += c5;  o.n6[1] += c0;  o.n6[2] += c0;  o.n6[3] += c5;
        o.n6[4] += c0;  o.n6[5] += c5;  o.n6[6] += c05;
        o.n5[0] += c5;  o.n5[1] += c1;  o.n5[2] += c15; o.n5[3] += c15;
        o.n5[4] += c1;  o.n5[5] += c5;  o.n5[6] += c15; o.n5[7] += c15;
        o.n4[0] += c4;  o.n4[1] += c1;  o.n4[2] += c14; o.n4[3] += c14;
        o.n4[4] += c14; o.n4[5] += c4;  o.n4[6] += c14; o.n4[7] += c1;
    }
    rp += STRIDE;
    {   // win row 3 = K6 r3, K5 r2, K4 r2, K3 r1 (center row)
        float c0 = rp[0], c1 = rp[1], c2 = rp[2], c3 = rp[3], c4 = rp[4], c5 = rp[5];
        float c05 = c0 + c5, c15 = c1 + c5, c14 = c1 + c4;
        r3s = (c2 + c3) + c4;
        cen3 = c2; cen4 = c3; cen5 = c4;
        o.v = c3;
        o.n6[0] += c5;  o.n6[1] += c0;  o.n6[2] += c0;  o.n6[3] += c5;
        o.n6[4] += c0;  o.n6[5] += c5;  o.n6[6] += c05;
        o.n5[0] += c5;  o.n5[1] += c1;  o.n5[2] += c1;  o.n5[3] += c5;
        o.n5[4] += c1;  o.n5[5] += c5;  o.n5[6] += c15; o.n5[7] += c15;
        o.n4[0] += c14; o.n4[1] += c14; o.n4[2] += c4;  o.n4[3] += c1;
        o.n4[4] += c14; o.n4[5] += c4;  o.n4[6] += c14; o.n4[7] += c1;
    }
    rp += STRIDE;
    {   // win row 4 = K6 r4, K5 r3, K4 r3, K3 r2
        float c0 = rp[0], c1 = rp[1], c2 = rp[2], c3 = rp[3], c4 = rp[4], c5 = rp[5];
        float c05 = c0 + c5, c15 = c1 + c5, c12 = c1 + c2, c34 = c3 + c4;
        float S4 = c12 + c34, c14 = c1 + c4;
        r4s = (c2 + c3) + c4;
        cen6 = c2; cen7 = c3; cen8 = c4;
        o.n6[0] += c05; o.n6[1] += c05; o.n6[2] += c0;  o.n6[3] += c5;
        o.n6[4] += c0;  o.n6[5] += c5;  o.n6[6] += c05;
        o.n5[0] += c15; o.n5[1] += c15; o.n5[2] += c1;  o.n5[3] += c5;
        o.n5[4] += c1;  o.n5[5] += c5;  o.n5[6] += c15; o.n5[7] += c15;
        o.n4[0] += S4;  o.n4[1] += S4;  o.n4[2] += c34; o.n4[3] += c12;
        o.n4[4] += S4;  o.n4[5] += S4;  o.n4[6] += c14; o.n4[7] += S4;
    }
    rp += STRIDE;
    {   // win row 5 = K6 r5, K5 r4
        float c0 = rp[0], c1 = rp[1], c2 = rp[2], c3 = rp[3], c4 = rp[4], c5 = rp[5];
        float c45 = c4 + c5, c12 = c1 + c2;
        float t = c3 + c45, S5 = c12 + t, S6 = S5 + c0;
        float c01 = c0 + c1, c05 = c0 + c5, c15 = c1 + c5;
        o.n6[0] += S6;  o.n6[1] += S6;  o.n6[2] += c01; o.n6[3] += c45;
        o.n6[4] += S6;  o.n6[5] += S6;  o.n6[6] += c05;
        o.n5[0] += S5;  o.n5[1] += S5;  o.n5[2] += c12; o.n5[3] += c45;
        o.n5[4] += S5;  o.n5[5] += S5;  o.n5[6] += c15; o.n5[7] += S5;
    }
    // K3: all 8 masks = S33 - center - one distinct cell
    float S33 = (r2s + r3s) + r4s;
    float T = S33 - cen4;
    o.n3[0] = T - cen3; o.n3[1] = T - cen7; o.n3[2] = T - cen5; o.n3[3] = T - cen1;
    o.n3[4] = T - cen0; o.n3[5] = T - cen6; o.n3[6] = T - cen8; o.n3[7] = T - cen2;
    return o;
}

// class index per mask into per-class constants; counts {7,9,10,11,13,16}
__constant__ __device__ const int CI4[8] = {1, 1, 1, 1, 2, 2, 2, 2};
__constant__ __device__ const int CI5[8] = {3, 3, 3, 3, 4, 4, 4, 4};
__constant__ __device__ const int CI6[7] = {4, 4, 4, 4, 5, 5, 5};

// PAIR=true: negA[6] = -(CC+m_c), s2m[6] = 2^m_c (shared-exp pairs).
// PAIR=false: plain endsig on direct only (edge blocks).
template <bool PAIR>
__device__ __forceinline__ void ssum_from_nc(const NC& a, const float* negA,
                                             const float* s2m, float& sD,
                                             float& sC) {
    float sd = 0.0f, sc = 0.0f;
#pragma unroll
    for (int k = 0; k < 8; k++) {
        if constexpr (PAIR) pair_term(a.n3[k], negA[0], s2m[0], sd, sc);
        else sd += endsig(a.n3[k]);
    }
#pragma unroll
    for (int k = 0; k < 8; k++) {
        if constexpr (PAIR) pair_term(a.n4[k], negA[CI4[k]], s2m[CI4[k]], sd, sc);
        else sd += endsig(a.n4[k]);
    }
#pragma unroll
    for (int k = 0; k < 8; k++) {
        if constexpr (PAIR) pair_term(a.n5[k], negA[CI5[k]], s2m[CI5[k]], sd, sc);
        else sd += endsig(a.n5[k]);
    }
#pragma unroll
    for (int k = 0; k < 7; k++) {
        if constexpr (PAIR) pair_term(a.n6[k], negA[CI6[k]], s2m[CI6[k]], sd, sc);
        else sd += endsig(a.n6[k]);
    }
    sD = sd;
    sC = sc;
}

// build per-class pair constants from M: cm = CC*(cnt*M-1), m = (cm-CC)/2
__device__ __forceinline__ void build_pair_consts(float M, float* negA,
                                                  float* s2m) {
    const float cntf[6] = {7.0f, 9.0f, 10.0f, 11.0f, 13.0f, 16.0f};
#pragma unroll
    for (int c = 0; c < 6; c++) {
        float cm = fmaf(cntf[c] * M, CC, -CC);
        float m = 0.5f * (cm - CC);
        negA[c] = -(CC + m);
        s2m[c] = exp2f_n(m);
    }
}

// ---------------- cp_quad: multi-level (R10 structure; (256,8) residency) ----
// z-slice -> (lvl = lvl_base + z>>3, b = z&7). lvl selects input pair + M
// slots; planes at cp + 4*(lvl-plane_lvl0)*NPIX. One merged dispatch = one
// residency tail. (256,8): request 8 waves/EU (VGPR<=64; was 48) — R12 showed
// cp stall-bound at ~41% occupancy, not issue-bound.
__global__ __launch_bounds__(256, 8) void cp_quad_kernel(
    const float* __restrict__ x0P, const float* __restrict__ x0G,
    const float* __restrict__ x1P, const float* __restrict__ x1G,
    const float* __restrict__ x2P, const float* __restrict__ x2G,
    const float* __restrict__ S, int lvl_base, int plane_lvl0,
    __half* __restrict__ cp) {
    __shared__ float win[2][21][48];
    const int lvl = lvl_base + (blockIdx.z >> 3);
    const int b = blockIdx.z & 7;
    const float* xP = (lvl == 0) ? x0P : (lvl == 1) ? x1P : x2P;
    const float* xG = (lvl == 0) ? x0G : (lvl == 1) ? x1G : x2G;
    const float MP = S[lvl], MG = S[3 + lvl];
    __half* cpb = cp + (size_t)(4 * (lvl - plane_lvl0)) * NPIX;

    const int oy0 = blockIdx.y * 16, ox0 = blockIdx.x * 16;
    const bool edge = (blockIdx.x == 0) | (blockIdx.x == (W / 16 - 1)) |
                      (blockIdx.y == 0) | (blockIdx.y == (H / 16 - 1));
    const int tid = threadIdx.y * 16 + threadIdx.x;
    const int ty = threadIdx.y, tx = threadIdx.x;
    const int o = b * HW + (oy0 + ty) * W + (ox0 + tx);

    if (!edge) {
        const float* pb = xP + b * HW + (oy0 - 3) * W + (ox0 - 3);
        const float* gb = xG + b * HW + (oy0 - 3) * W + (ox0 - 3);
        for (int i = tid; i < 21 * 21; i += 256) {
            int r = i / 21, c = i % 21;
            win[0][r][c] = pb[r * W + c];
            win[1][r][c] = gb[r * W + c];
        }
        __syncthreads();
        float negA[6], s2m[6], sPd, sPc, sGd, sGc;
        build_pair_consts(MP, negA, s2m);
        NC a = sweep<48>(&win[0][ty][tx]);
        ssum_from_nc<true>(a, negA, s2m, sPd, sPc);
        build_pair_consts(MG, negA, s2m);
        NC g = sweep<48>(&win[1][ty][tx]);
        ssum_from_nc<true>(g, negA, s2m, sGd, sGc);
        cpb[0 * NPIX + o] = __float2half(sig_cp(a.v * sPd));
        cpb[1 * NPIX + o] = __float2half(sig_cp(g.v * sGd));
        cpb[2 * NPIX + o] = __float2half(sig_cp((MP - a.v) * sPc));
        cpb[3 * NPIX + o] = __float2half(sig_cp((MG - g.v) * sGc));
    } else {
        const float* pb = xP + b * HW;
        const float* gb = xG + b * HW;
        // phase A: direct planes
        for (int i = tid; i < 21 * 21; i += 256) {
            int r = i / 21, c = i % 21;
            int pr = oy0 - 2 + r;  // padded coords (0..513 valid)
            int pc = ox0 - 2 + c;
            float vP, vG;
            if (pr < 0 || pr > H + 1 || pc < 0 || pc > W + 1) {
                vP = vG = 0.0f;  // conv zero-pad
            } else if (pr == 0 || pr == H + 1 || pc == 0 || pc == W + 1) {
                vP = vG = 1.0f;  // image 1-pad
            } else {
                vP = pb[(pr - 1) * W + (pc - 1)];
                vG = gb[(pr - 1) * W + (pc - 1)];
            }
            win[0][r][c] = vP; win[1][r][c] = vG;
        }
        __syncthreads();
        float sPd, sPc, sGd, sGc, junk, vPd, vGd;
        NC a = sweep<48>(&win[0][ty][tx]);
        ssum_from_nc<false>(a, nullptr, nullptr, sPd, junk);  vPd = a.v;
        NC g = sweep<48>(&win[1][ty][tx]);
        ssum_from_nc<false>(g, nullptr, nullptr, sGd, junk);  vGd = g.v;
        cpb[0 * NPIX + o] = __float2half(sig_cp(vPd * sPd));
        cpb[1 * NPIX + o] = __float2half(sig_cp(vGd * sGd));
        __syncthreads();  // all reads of direct planes done
        // phase B: complement planes
        for (int i = tid; i < 21 * 21; i += 256) {
            int r = i / 21, c = i % 21;
            int pr = oy0 - 2 + r;
            int pc = ox0 - 2 + c;
            float vP, vG;
            if (pr < 0 || pr > H + 1 || pc < 0 || pc > W + 1) {
                vP = vG = 0.0f;
            } else if (pr == 0 || pr == H + 1 || pc == 0 || pc == W + 1) {
                vP = vG = 1.0f;
            } else {
                vP = MP - pb[(pr - 1) * W + (pc - 1)];
                vG = MG - gb[(pr - 1) * W + (pc - 1)];
            }
            win[0][r][c] = vP; win[1][r][c] = vG;
        }
        __syncthreads();
        NC ac = sweep<48>(&win[0][ty][tx]);
        ssum_from_nc<false>(ac, nullptr, nullptr, sPc, junk);
        NC gc = sweep<48>(&win[1][ty][tx]);
        ssum_from_nc<false>(gc, nullptr, nullptr, sGc, junk);
        cpb[2 * NPIX + o] = __float2half(sig_cp(ac.v * sPc));
        cpb[3 * NPIX + o] = __float2half(sig_cp(gc.v * sGc));
    }
}

// ---------------- dil_diff: 8 rows/thread, f16 input, multi-level ------------
__device__ __forceinline__ void dil_rows10(const __half* __restrict__ p,
                                           int base, int y0, int x,
                                           float rs[10]) {
#pragma unroll
    for (int j = 0; j < 10; j++) {
        int yy = y0 - 1 + j;
        float l = 0, m = 0, r = 0;
        if (yy >= 0 && yy < H) {  // wave-uniform
            int rb = base + yy * W;
            m = __half2float(p[rb + x]);
            int xl = x > 0 ? x - 1 : 0;
            int xr = x < W - 1 ? x + 1 : W - 1;
            float lv = __half2float(p[rb + xl]);
            float rv = __half2float(p[rb + xr]);
            l = x > 0 ? lv : 0.0f;
            r = x < W - 1 ? rv : 0.0f;
        }
        rs[j] = (l + m) + r;
    }
}

__global__ __launch_bounds__(256) void dil_diff2_kernel(
    const __half* __restrict__ cp, float* __restrict__ partial) {
    const int plane_grp = blockIdx.x >> 10;  // NBD=1024 blocks per level
    const int r = blockIdx.x & (NBD - 1);
    const __half* cpb = cp + (size_t)(4 * plane_grp) * NPIX;
    const int T = r * 256 + threadIdx.x;
    const int x = T & (W - 1);
    const int g = T >> 9;
    const int y0 = (g & 63) << 3;  // 64 rowgroups of 8 rows
    const int b = g >> 6;
    const int base = b * HW;

    float rs0[10], rs1[10], rs2[10], rs3[10];
    dil_rows10(cpb + 0 * NPIX, base, y0, x, rs0);
    dil_rows10(cpb + 1 * NPIX, base, y0, x, rs1);
    dil_rows10(cpb + 2 * NPIX, base, y0, x, rs2);
    dil_rows10(cpb + 3 * NPIX, base, y0, x, rs3);

    float s = 0.0f;
#pragma unroll
    for (int i = 0; i < 8; i++) {
        float s0 = (rs0[i] + rs0[i + 1]) + rs0[i + 2];
        float s1 = (rs1[i] + rs1[i + 1]) + rs1[i + 2];
        float s2 = (rs2[i] + rs2[i + 1]) + rs2[i + 2];
        float s3 = (rs3[i] + rs3[i + 1]) + rs3[i + 2];
        float d1 = fminf(s0, 1.0f) - fminf(s1, 1.0f);
        float d2 = fminf(s2, 1.0f) - fminf(s3, 1.0f);
        s += fmaf(d1, d1, d2 * d2);
    }
    s = wave_sum(s);
    __shared__ float red[4];
    int tid = threadIdx.x;
    if ((tid & 63) == 0) red[tid >> 6] = s;
    __syncthreads();
    if (tid == 0) partial[blockIdx.x] = (red[0] + red[1]) + (red[2] + red[3]);
}

// ---------------- cross-conv 4px/thread helper -------------------------------
__device__ __forceinline__ void cross4(const float* __restrict__ xp, int idx,
                                       int y, int c, float4& ctr, float t[4]) {
    const float4* v = (const float4*)(xp + idx);
    ctr = v[0];
    float4 up = (y > 0) ? *(const float4*)(xp + idx - W)
                        : make_float4(0, 0, 0, 0);
    float4 dn = (y < H - 1) ? *(const float4*)(xp + idx + W)
                            : make_float4(0, 0, 0, 0);
    float lf = (c > 0) ? xp[idx - 1] : 0.0f;
    float rt = (c < W - 4) ? xp[idx + 4] : 0.0f;
    t[0] = (up.x + dn.x) + (lf + ctr.y);
    t[1] = (up.y + dn.y) + (ctr.x + ctr.z);
    t[2] = (up.z + dn.z) + (ctr.y + ctr.w);
    t[3] = (up.w + dn.w) + (ctr.z + rt);
}

// ---------------- erosion: cross-conv max pass -> float4 partial/block -------
__global__ __launch_bounds__(256) void cross_max_both_kernel(
    const float* __restrict__ xP, const float* __restrict__ xG,
    float4* __restrict__ partial) {
    float mtP = 0, mtG = 0, mrP = 0, mrG = 0;
    for (int T = blockIdx.x * 256 + threadIdx.x; T < NPIX / 4; T += NB1 * 256) {
        int idx = T * 4;
        int i = idx & (HW - 1);
        int y = i >> 9;
        int c = i & (W - 1);
        float4 ctr;
        float t[4];
        cross4(xP, idx, y, c, ctr, t);
        mtP = fmaxf(mtP, fmaxf(fmaxf(t[0], t[1]), fmaxf(t[2], t[3])));
        mrP = fmaxf(mrP, fmaxf(fmaxf(ctr.x, ctr.y), fmaxf(ctr.z, ctr.w)));
        cross4(xG, idx, y, c, ctr, t);
        mtG = fmaxf(mtG, fmaxf(fmaxf(t[0], t[1]), fmaxf(t[2], t[3])));
        mrG = fmaxf(mrG, fmaxf(fmaxf(ctr.x, ctr.y), fmaxf(ctr.z, ctr.w)));
    }
    mtP = wave_max(mtP); mtG = wave_max(mtG);
    mrP = wave_max(mrP); mrG = wave_max(mrG);
    __shared__ float red[4][4];
    int tid = threadIdx.x;
    if ((tid & 63) == 0) {
        int w = tid >> 6;
        red[w][0] = mtP; red[w][1] = mtG; red[w][2] = mrP; red[w][3] = mrG;
    }
    __syncthreads();
    if (tid == 0) {
        float4 r;
        r.x = fmaxf(fmaxf(red[0][0], red[1][0]), fmaxf(red[2][0], red[3][0]));
        r.y = fmaxf(fmaxf(red[0][1], red[1][1]), fmaxf(red[2][1], red[3][1]));
        r.z = fmaxf(fmaxf(red[0][2], red[1][2]), fmaxf(red[2][2], red[3][2]));
        r.w = fmaxf(fmaxf(red[0][3], red[1][3]), fmaxf(red[2][3], red[3][3]));
        partial[blockIdx.x] = r;
    }
}

// ---------------- erosion: fused PM-reduce + cross conv + normalize ----------
__global__ __launch_bounds__(256) void erode_both_kernel(
    const float* __restrict__ xP, const float* __restrict__ xG,
    const float4* __restrict__ PM,
    float* __restrict__ yP, float* __restrict__ yG,
    float* ymaxP, float* ymaxG, float* rmaxP, float* rmaxG) {
    // redundant per-block PM reduce (16KB, L2-resident)
    float a = 0, bm = 0, c4 = 0, d4 = 0;
    {
        int t = threadIdx.x;
#pragma unroll
        for (int k = 0; k < NB1 / 256; k++) {
            float4 p = PM[t + k * 256];
            a = fmaxf(a, p.x); bm = fmaxf(bm, p.y);
            c4 = fmaxf(c4, p.z); d4 = fmaxf(d4, p.w);
        }
        a = wave_max(a); bm = wave_max(bm); c4 = wave_max(c4); d4 = wave_max(d4);
        __shared__ float red[4][4];
        if ((t & 63) == 0) {
            int w = t >> 6;
            red[w][0] = a; red[w][1] = bm; red[w][2] = c4; red[w][3] = d4;
        }
        __syncthreads();
        a  = fmaxf(fmaxf(red[0][0], red[1][0]), fmaxf(red[2][0], red[3][0]));
        bm = fmaxf(fmaxf(red[0][1], red[1][1]), fmaxf(red[2][1], red[3][1]));
        c4 = fmaxf(fmaxf(red[0][2], red[1][2]), fmaxf(red[2][2], red[3][2]));
        d4 = fmaxf(fmaxf(red[0][3], red[1][3]), fmaxf(red[2][3], red[3][3]));
    }
    const float tP_max = a, tG_max = bm;
    const float invP = rcpf(tP_max + 1e-8f);
    const float invG = rcpf(tG_max + 1e-8f);

    const int T = blockIdx.x * 256 + threadIdx.x;  // 2048 blocks cover NPIX/4
    if (T < NPIX / 4) {
        int idx = T * 4;
        int i = idx & (HW - 1);
        int y = i >> 9;
        int c = i & (W - 1);
        float4 ctr;
        float t[4], o[4];
        cross4(xP, idx, y, c, ctr, t);
#pragma unroll
        for (int k = 0; k < 4; k++) o[k] = sig_er(t[k] * invP);
        *(float4*)(yP + idx) = make_float4(o[0], o[1], o[2], o[3]);
        cross4(xG, idx, y, c, ctr, t);
#pragma unroll
        for (int k = 0; k < 4; k++) o[k] = sig_er(t[k] * invG);
        *(float4*)(yG + idx) = make_float4(o[0], o[1], o[2], o[3]);
    }
    if (blockIdx.x == 0 && threadIdx.x == 0) {
        *ymaxP = sig_er(tP_max * invP);
        *ymaxG = sig_er(tG_max * invG);
        *rmaxP = c4;
        *rmaxG = d4;
    }
}

// ---------------- final: sum 3*NBD partials, /B ------------------------------
__global__ __launch_bounds__(1024) void finalize_kernel(
    const float* __restrict__ PS, float* out) {
    int t = threadIdx.x;
    float s = PS[t] + PS[t + NBD] + PS[t + 2 * NBD];
    s = wave_sum(s);
    __shared__ float red[16];
    if ((t & 63) == 0) red[t >> 6] = s;
    __syncthreads();
    if (t == 0) {
        float tot = 0.0f;
#pragma unroll
        for (int i = 0; i < 16; i++) tot += red[i];
        out[0] = tot * (1.0f / (float)B);
    }
}

// ---------------- launch -----------------------------------------------------
extern "C" void kernel_launch(void* const* d_in, const int* in_sizes, int n_in,
                              void* d_out, int out_size, void* d_ws, size_t ws_size,
                              hipStream_t stream) {
    (void)in_sizes; (void)n_in; (void)out_size;
    const float* pred = (const float*)d_in[0];
    const float* gt   = (const float*)d_in[1];
    float* out = (float*)d_out;

    // ws (floats): S[64] | PM[4*NB1] | PS[3*NBD] | P1,G1,P2,G2 | CP (f16)
    float* S  = (float*)d_ws;
    float4* PM = (float4*)(S + 64);
    float* PS = S + 64 + 4 * NB1;
    float* P1 = PS + 3 * NBD;
    float* G1 = P1 + NPIX;
    float* P2 = G1 + NPIX;
    float* G2 = P2 + NPIX;
    __half* CP = (__half*)(G2 + NPIX);

    // merged path needs 12 f16 CP planes (48MB); fallback (R9 schedule) needs 4
    const size_t base_b = (size_t)(64 + 4 * NB1 + 3 * NBD) * 4 +
                          (size_t)4 * NPIX * 4;
    const bool merged = ws_size >= base_b + (size_t)12 * NPIX * 2;

    const dim3 b1(256), g1(NB1), gE(NPIX / 4 / 256);
    const dim3 b2(16, 16, 1);

    // erosion chain
    cross_max_both_kernel<<<g1, b1, 0, stream>>>(pred, gt, PM);
    erode_both_kernel<<<gE, b1, 0, stream>>>(pred, gt, PM, P1, G1,
                                             S + 1, S + 4, S + 0, S + 3);
    cross_max_both_kernel<<<g1, b1, 0, stream>>>(P1, G1, PM);
    erode_both_kernel<<<gE, b1, 0, stream>>>(P1, G1, PM, P2, G2,
                                             S + 2, S + 5, S + 12, S + 13);

    if (merged) {
        // all 3 levels in one cp dispatch (one tail) + one dil dispatch
        cp_quad_kernel<<<dim3(W / 16, H / 16, 3 * B), b2, 0, stream>>>(
            pred, gt, P1, G1, P2, G2, S, 0, 0, CP);
        dil_diff2_kernel<<<dim3(3 * NBD), b1, 0, stream>>>(CP, PS);
    } else {
        for (int lvl = 0; lvl < 3; lvl++) {
            cp_quad_kernel<<<dim3(W / 16, H / 16, B), b2, 0, stream>>>(
                pred, gt, P1, G1, P2, G2, S, lvl, lvl, CP);
            dil_diff2_kernel<<<dim3(NBD), b1, 0, stream>>>(CP, PS + lvl * NBD);
        }
    }

    finalize_kernel<<<1, 1024, 0, stream>>>(PS, out);
}